// Round 1
// baseline (235.616 us; speedup 1.0000x reference)
//
#include <hip/hip_runtime.h>
#include <cstdint>
#include <cstddef>

#define NEG_C 1000000000000.0f

typedef __bf16 bf16x8 __attribute__((ext_vector_type(8)));
typedef float f32x4 __attribute__((ext_vector_type(4)));

union Frag {
    int4 i;
    bf16x8 b;
};

__device__ __forceinline__ unsigned short f32_to_bf16_rne(float f) {
    unsigned int u = __float_as_uint(f);
    u += 0x7fffu + ((u >> 16) & 1u);
    return (unsigned short)(u >> 16);
}
__device__ __forceinline__ float bf16u_to_f32(unsigned short h) {
    return __uint_as_float(((unsigned int)h) << 16);
}

// ---------------------------------------------------------------- convert
// hidden f32 [16*512*768] -> bf16, vectorized (float4 -> ushort4)
__global__ void convert_hidden_kernel(const float* __restrict__ src,
                                      unsigned short* __restrict__ dst, int n4) {
    int idx = blockIdx.x * blockDim.x + threadIdx.x;
    if (idx >= n4) return;
    float4 v = ((const float4*)src)[idx];
    ushort4 o;
    o.x = f32_to_bf16_rne(v.x);
    o.y = f32_to_bf16_rne(v.y);
    o.z = f32_to_bf16_rne(v.z);
    o.w = f32_to_bf16_rne(v.w);
    ((ushort4*)dst)[idx] = o;
}

// ---------------------------------------------------------------- W transpose
// W f32 [768][1152] -> WT bf16 [1152][768]  (N-major, K contiguous for MFMA frags)
__global__ void transpose_w_kernel(const float* __restrict__ W,
                                   unsigned short* __restrict__ WT) {
    __shared__ unsigned short tile[32][33];  // +1 pad: no bank conflict
    int bx = blockIdx.x;              // n-tile: 0..35
    int by = blockIdx.y;              // k-tile: 0..23
    int x = threadIdx.x & 31;
    int y0 = threadIdx.x >> 5;        // 0..7
#pragma unroll
    for (int yy = 0; yy < 32; yy += 8) {
        int k = by * 32 + y0 + yy;
        int n = bx * 32 + x;
        tile[y0 + yy][x] = f32_to_bf16_rne(W[(size_t)k * 1152 + n]);
    }
    __syncthreads();
#pragma unroll
    for (int yy = 0; yy < 32; yy += 8) {
        int n = bx * 32 + y0 + yy;
        int k = by * 32 + x;
        WT[(size_t)n * 768 + k] = tile[x][y0 + yy];
    }
}

// ---------------------------------------------------------------- GEMM1
// proj[8192][1152] (bf16) = Ah[8192][768] @ W[768][1152] + bias
// WT is [1152][768] (B^T). 128x128 tile, 4 waves, 4x4 frags of 16x16x32, BK=32.
__global__ __launch_bounds__(256, 2) void gemm1_kernel(
    const unsigned short* __restrict__ Ah, const unsigned short* __restrict__ WT,
    const float* __restrict__ bias, unsigned short* __restrict__ proj) {
    const int K = 768, N = 1152;
    __shared__ unsigned short As[128 * 32];  // [m][k]
    __shared__ unsigned short Bs[128 * 32];  // [n][k]
    int tid = threadIdx.x;
    int lane = tid & 63;
    int wave = tid >> 6;
    int bm = blockIdx.x * 128;
    int bn = blockIdx.y * 128;
    int wm = (wave & 1) * 64;
    int wn = (wave >> 1) * 64;
    int col_l = lane & 15;
    int kg = (lane >> 4) * 8;

    f32x4 acc[4][4] = {};

    for (int k0 = 0; k0 < K; k0 += 32) {
        __syncthreads();
#pragma unroll
        for (int p = 0; p < 2; ++p) {
            int c = p * 256 + tid;     // 0..511
            int row = c >> 2;          // 0..127
            int ko = (c & 3) * 8;      // 0,8,16,24
            *(int4*)(As + row * 32 + ko) =
                *(const int4*)(Ah + (size_t)(bm + row) * K + k0 + ko);
            *(int4*)(Bs + row * 32 + ko) =
                *(const int4*)(WT + (size_t)(bn + row) * K + k0 + ko);
        }
        __syncthreads();
        Frag a[4], bfr[4];
#pragma unroll
        for (int i = 0; i < 4; ++i) {
            a[i].i   = *(const int4*)(As + (wm + i * 16 + col_l) * 32 + kg);
            bfr[i].i = *(const int4*)(Bs + (wn + i * 16 + col_l) * 32 + kg);
        }
#pragma unroll
        for (int i = 0; i < 4; ++i)
#pragma unroll
            for (int j = 0; j < 4; ++j)
                acc[i][j] = __builtin_amdgcn_mfma_f32_16x16x32_bf16(
                    a[i].b, bfr[j].b, acc[i][j], 0, 0, 0);
    }
    // epilogue: += bias, -> bf16
    int row_q = (lane >> 4) * 4;
#pragma unroll
    for (int i = 0; i < 4; ++i) {
#pragma unroll
        for (int j = 0; j < 4; ++j) {
            int gn = bn + wn + j * 16 + col_l;
            float bb = bias[gn];
#pragma unroll
            for (int r = 0; r < 4; ++r) {
                int gm = bm + wm + i * 16 + row_q + r;
                proj[(size_t)gm * N + gn] = f32_to_bf16_rne(acc[i][j][r] + bb);
            }
        }
    }
}

// ---------------------------------------------------------------- RoPE (in-place)
// proj viewed as [16][512][9][128] bf16; q = [0:64), k = [64:128).
// One thread per interleaved pair (handles both q-pair and k-pair).
__global__ void rope_kernel(unsigned short* __restrict__ proj) {
    int idx = blockIdx.x * blockDim.x + threadIdx.x;  // 16*512*9*32 = 2359296
    int i = idx & 31;              // pair index
    int rest = idx >> 5;
    int t = rest % 9;
    int rest2 = rest / 9;
    int s = rest2 & 511;
    int b = rest2 >> 9;
    // inv = 10000^{-i/32} = 2^{-i*log2(10000)/32}
    float inv = exp2f(-0.41524101186091903f * (float)i);
    float ang = (float)s * inv;
    float sn, cs;
    sincosf(ang, &sn, &cs);
    unsigned int* p = (unsigned int*)(proj + (((size_t)(b * 512 + s) * 9) + t) * 128);
    unsigned int q = p[i];
    float q0 = bf16u_to_f32((unsigned short)(q & 0xffffu));
    float q1 = bf16u_to_f32((unsigned short)(q >> 16));
    float r0 = q0 * cs - q1 * sn;
    float r1 = q1 * cs + q0 * sn;
    p[i] = (unsigned int)f32_to_bf16_rne(r0) | ((unsigned int)f32_to_bf16_rne(r1) << 16);
    unsigned int k = p[32 + i];
    float k0 = bf16u_to_f32((unsigned short)(k & 0xffffu));
    float k1 = bf16u_to_f32((unsigned short)(k >> 16));
    float t0 = k0 * cs - k1 * sn;
    float t1 = k1 * cs + k0 * sn;
    p[32 + i] = (unsigned int)f32_to_bf16_rne(t0) | ((unsigned int)f32_to_bf16_rne(t1) << 16);
}

// ---------------------------------------------------------------- GEMM2 + mask
// out[b][t][m][n] = (sum_d q[b,m,t,d]*k[b,n,t,d] * pm[b,n] - (1-pm)*NEG - (m>n)*NEG)/8
__global__ __launch_bounds__(256, 2) void gemm2_kernel(
    const unsigned short* __restrict__ proj, const int* __restrict__ mask,
    float* __restrict__ out) {
    __shared__ unsigned short Qs[128 * 64];
    __shared__ unsigned short Ks[128 * 64];
    int bid = blockIdx.x;          // 144*16 = 2304
    int batch = bid >> 4;          // 0..143
    int tl = bid & 15;
    int tm = tl >> 2, tn = tl & 3;
    int b = batch / 9, t = batch - b * 9;
    int tid = threadIdx.x, lane = tid & 63, wave = tid >> 6;
    int wm = (wave & 1) * 64, wn = (wave >> 1) * 64;
    int col_l = lane & 15;
    size_t out_base = ((size_t)b * 9 + t) * 512 * 512;

    if (tm > tn) {
        // entire 128x128 tile is strictly below the diagonal (m>n for all):
        // ref value = (L*pm - (1-pm)*NEG - NEG)/8; dropping L*pm costs |L|/8 ~ 4 << 2.5e9 threshold
#pragma unroll 4
        for (int r = 0; r < 128; r += 8) {
            int row = r + (tid >> 5);
            int c4 = (tid & 31) * 4;
            int gm = tm * 128 + row;
            int gn = tn * 128 + c4;
            float4 v;
            float* po = out + out_base + (size_t)gm * 512 + gn;
#pragma unroll
            for (int q = 0; q < 4; ++q) {
                float pm = (float)mask[b * 512 + gn + q];
                ((float*)&v)[q] = (-(1.0f - pm) * NEG_C - NEG_C) * 0.125f;
            }
            *(float4*)po = v;
        }
        return;
    }

    // stage Q rows (tm tile) and K rows (tn tile): 128 rows x 64 bf16 each
#pragma unroll
    for (int p = 0; p < 4; ++p) {
        int c = p * 256 + tid;   // 0..1023
        int row = c >> 3;        // 0..127
        int ko = (c & 7) * 8;    // 0..56
        *(int4*)(Qs + row * 64 + ko) = *(const int4*)(
            proj + (((size_t)(b * 512 + tm * 128 + row) * 9) + t) * 128 + ko);
        *(int4*)(Ks + row * 64 + ko) = *(const int4*)(
            proj + (((size_t)(b * 512 + tn * 128 + row) * 9) + t) * 128 + 64 + ko);
    }
    __syncthreads();

    f32x4 acc[4][4] = {};
#pragma unroll
    for (int ks = 0; ks < 2; ++ks) {
        Frag a[4], bfr[4];
        int kg = ks * 32 + (lane >> 4) * 8;
#pragma unroll
        for (int i = 0; i < 4; ++i) {
            a[i].i   = *(const int4*)(Qs + (wm + i * 16 + col_l) * 64 + kg);
            bfr[i].i = *(const int4*)(Ks + (wn + i * 16 + col_l) * 64 + kg);
        }
#pragma unroll
        for (int i = 0; i < 4; ++i)
#pragma unroll
            for (int j = 0; j < 4; ++j)
                acc[i][j] = __builtin_amdgcn_mfma_f32_16x16x32_bf16(
                    a[i].b, bfr[j].b, acc[i][j], 0, 0, 0);
    }

    int row_q = (lane >> 4) * 4;
#pragma unroll
    for (int i = 0; i < 4; ++i) {
#pragma unroll
        for (int j = 0; j < 4; ++j) {
            int gn = tn * 128 + wn + j * 16 + col_l;
            float pm = (float)mask[b * 512 + gn];
#pragma unroll
            for (int r = 0; r < 4; ++r) {
                int gm = tm * 128 + wm + i * 16 + row_q + r;
                float v = acc[i][j][r] * pm - (1.0f - pm) * NEG_C;
                if (gm > gn) v -= NEG_C;
                out[out_base + (size_t)gm * 512 + gn] = v * 0.125f;
            }
        }
    }
}

// ---------------------------------------------------------------- launch
extern "C" void kernel_launch(void* const* d_in, const int* in_sizes, int n_in,
                              void* d_out, int out_size, void* d_ws, size_t ws_size,
                              hipStream_t stream) {
    const float* hidden = (const float*)d_in[0];   // [16][512][768]
    const float* W      = (const float*)d_in[1];   // [768][1152]
    const float* bias   = (const float*)d_in[2];   // [1152]
    const int*   mask   = (const int*)d_in[3];     // [16][512]
    float* out = (float*)d_out;                    // [16][9][512][512]

    char* ws = (char*)d_ws;
    unsigned short* Ah   = (unsigned short*)(ws);              // 8192*768  bf16 (12.6 MB)
    unsigned short* WT   = (unsigned short*)(ws + 12582912);   // 1152*768  bf16 ( 1.8 MB)
    unsigned short* proj = (unsigned short*)(ws + 14352384);   // 8192*1152 bf16 (18.9 MB)

    convert_hidden_kernel<<<6144, 256, 0, stream>>>(hidden, Ah, 1572864);
    dim3 gt(36, 24);
    transpose_w_kernel<<<gt, 256, 0, stream>>>(W, WT);
    dim3 g1(64, 9);
    gemm1_kernel<<<g1, 256, 0, stream>>>(Ah, WT, bias, proj);
    rope_kernel<<<9216, 256, 0, stream>>>(proj);
    gemm2_kernel<<<2304, 256, 0, stream>>>(proj, mask, out);
}